// Round 2
// baseline (40579.922 us; speedup 1.0000x reference)
//
#include <hip/hip_runtime.h>
#include <hip/hip_bf16.h>
#include <hip/hip_fp16.h>
#include <stdint.h>

#define B_ 128
#define S_ 512
#define E_ 256
#define H2_ 512
#define G_ 1024      // 4*E
#define DG_ 2048     // 4*H2
#define M_ (B_*S_)   // 65536

typedef float f32x4 __attribute__((ext_vector_type(4)));
typedef short s16x8 __attribute__((ext_vector_type(8)));
typedef _Float16 h16x2 __attribute__((ext_vector_type(2)));

__device__ __forceinline__ float sigm(float x){ return 1.f/(1.f+__expf(-x)); }
__device__ __forceinline__ float tanh_f(float x){ return 1.f - 2.f/(__expf(2.f*x)+1.f); }

// ---------------- fp8 e4m3fn encode/decode ----------------
__device__ __forceinline__ uint32_t enc_e4m3(float f){
  uint32_t u = __float_as_uint(f);
  uint32_t s = (u >> 24) & 0x80u;
  float af = fabsf(f);
  if (!(af > 0.f)) return s;
  if (af >= 448.f) return s | 0x7Eu;
  int ex = (int)((u >> 23) & 0xFF) - 127;
  uint32_t man = u & 0x7FFFFFu;
  int bexp = ex + 7;
  if (bexp <= 0){
    uint32_t qi = (uint32_t)rintf(af * 512.f);
    if (qi > 8u) qi = 8u;
    return s | qi;
  }
  uint32_t keep = man >> 20;
  uint32_t rest = man & 0xFFFFFu;
  const uint32_t half = 0x80000u;
  if (rest > half || (rest == half && (keep & 1u))) keep++;
  if (keep == 8u){ keep = 0u; bexp++; }
  if (bexp >= 16) return s | 0x7Eu;
  if (bexp == 15 && keep == 7u) keep = 6u; // avoid NaN encoding
  return s | ((uint32_t)bexp << 3) | keep;
}

__device__ __forceinline__ float dec_e4m3(uint32_t byte){
  uint32_t s = (byte & 0x80u) << 24;
  uint32_t e = (byte >> 3) & 0xFu;
  uint32_t m = byte & 7u;
  float v;
  if (e == 0) v = (float)m * 0.001953125f;
  else v = __uint_as_float(((e + 120u) << 23) | (m << 20));
  return __uint_as_float(__float_as_uint(v) | s);
}

__device__ __forceinline__ void fp8x4_to_f32x4(uint32_t w, float* o){
#if __has_builtin(__builtin_amdgcn_cvt_pk_f32_fp8)
  auto lo = __builtin_amdgcn_cvt_pk_f32_fp8((int)w, false);
  auto hi = __builtin_amdgcn_cvt_pk_f32_fp8((int)w, true);
  o[0]=lo[0]; o[1]=lo[1]; o[2]=hi[0]; o[3]=hi[1];
#else
  o[0]=dec_e4m3(w & 0xFFu); o[1]=dec_e4m3((w>>8)&0xFFu);
  o[2]=dec_e4m3((w>>16)&0xFFu); o[3]=dec_e4m3(w>>24);
#endif
}

__device__ __forceinline__ float dot2_f16(uint32_t a, uint32_t b, float acc){
#if __has_builtin(__builtin_amdgcn_fdot2)
  return __builtin_amdgcn_fdot2(__builtin_bit_cast(h16x2,a), __builtin_bit_cast(h16x2,b), acc, false);
#else
  __half2 ah = __builtin_bit_cast(__half2, a), bh = __builtin_bit_cast(__half2, b);
  float2 af = __half22float2(ah), bf = __half22float2(bh);
  return fmaf(af.x, bf.x, fmaf(af.y, bf.y, acc));
#endif
}

// ---------------- weight prep ----------------
__global__ __launch_bounds__(512) void k_prep_enc(
    const float* __restrict__ wf, const float* __restrict__ wb,
    const float* __restrict__ bihf, const float* __restrict__ bhhf,
    const float* __restrict__ bihb, const float* __restrict__ bhhb,
    ushort* __restrict__ Wenc, float* __restrict__ bsum){
  int n = blockIdx.x, d = threadIdx.x;
  const float* src = (n < G_) ? (wf + (size_t)n*H2_) : (wb + (size_t)(n-G_)*H2_);
  __hip_bfloat16 h = __float2bfloat16(src[d]);
  Wenc[(size_t)n*H2_ + d] = __builtin_bit_cast(ushort, h);
  if (d == 0) bsum[n] = (n < G_) ? (bihf[n] + bhhf[n]) : (bihb[n-G_] + bhhb[n-G_]);
}

__global__ __launch_bounds__(256) void k_prep_whh(
    const float* __restrict__ whf, const float* __restrict__ whb, uint8_t* __restrict__ whh8){
  int r = blockIdx.x; int d = threadIdx.x;
  int dir = r >> 10, g = r & 1023;
  float v = dir ? whb[(size_t)g*E_ + d] : whf[(size_t)g*E_ + d];
  whh8[((size_t)dir*G_ + g)*E_ + d] = (uint8_t)enc_e4m3(v);
}

__global__ __launch_bounds__(64) void k_prep_dec(
    const float* __restrict__ wd, const float* __restrict__ bih, const float* __restrict__ bhh,
    uint4* __restrict__ wdt, float* __restrict__ bsumd){
  int row = blockIdx.x, u = threadIdx.x; // u in [0,64)
  const float* src = wd + (size_t)row*H2_ + u*8;
  union { _Float16 h[8]; uint4 q; } pk;
  #pragma unroll
  for (int i=0;i<8;i++) pk.h[i] = (_Float16)src[i];
  wdt[(size_t)u*DG_ + row] = pk.q;
  if (u == 0) bsumd[row] = bih[row] + bhh[row];
}

// ---------------- input stats ----------------
__global__ __launch_bounds__(512) void k_xstat(
    const float* __restrict__ X, float* __restrict__ SX, float* __restrict__ SX2){
  int b = blockIdx.x, d = threadIdx.x;
  const float* xb = X + (size_t)b*S_*H2_;
  float s=0.f, s2=0.f;
  for (int t=0;t<S_;++t){ float v = xb[(size_t)t*H2_ + d]; s += v; s2 = fmaf(v,v,s2); }
  SX[(size_t)b*H2_+d]=s; SX2[(size_t)b*H2_+d]=s2;
}

// ---------------- pre-GEMM: pre[m][n] = X[m][:] . Wenc[n][:] + bsum[n] ----------------
__global__ __launch_bounds__(256) void k_gemm_pre(
    const float* __restrict__ X, const ushort* __restrict__ Wenc,
    const float* __restrict__ bsum, __hip_bfloat16* __restrict__ pre){
  __shared__ ushort As[128][64];
  __shared__ ushort Bs[128][64];
  int n0 = blockIdx.x * 128, m0 = blockIdx.y * 128;
  int tid = threadIdx.x, lane = tid & 63, wid = tid >> 6;
  int wr = wid >> 1, wc = wid & 1;
  f32x4 acc[4][4] = {};
  for (int kt=0; kt<8; ++kt){
    int k0 = kt*64;
    #pragma unroll
    for (int it=0; it<4; ++it){
      int slot = tid + it*256;
      int r = slot >> 3, c8 = (slot & 7)*8;
      const float* ap = X + (size_t)(m0+r)*512 + k0 + c8;
      float4 a0 = *(const float4*)ap;
      float4 a1 = *(const float4*)(ap+4);
      union { __hip_bfloat16 h[8]; uint4 q; } pk;
      pk.h[0]=__float2bfloat16(a0.x); pk.h[1]=__float2bfloat16(a0.y);
      pk.h[2]=__float2bfloat16(a0.z); pk.h[3]=__float2bfloat16(a0.w);
      pk.h[4]=__float2bfloat16(a1.x); pk.h[5]=__float2bfloat16(a1.y);
      pk.h[6]=__float2bfloat16(a1.z); pk.h[7]=__float2bfloat16(a1.w);
      *(uint4*)&As[r][c8] = pk.q;
      *(uint4*)&Bs[r][c8] = *(const uint4*)(Wenc + (size_t)(n0+r)*512 + k0 + c8);
    }
    __syncthreads();
    #pragma unroll
    for (int kk=0; kk<2; ++kk){
      int krow = kk*32 + (lane>>4)*8;
      s16x8 af[4], bf[4];
      #pragma unroll
      for (int mi=0;mi<4;mi++) af[mi] = *(const s16x8*)&As[wr*64+mi*16+(lane&15)][krow];
      #pragma unroll
      for (int ni=0;ni<4;ni++) bf[ni] = *(const s16x8*)&Bs[wc*64+ni*16+(lane&15)][krow];
      #pragma unroll
      for (int mi=0;mi<4;mi++){
        #pragma unroll
        for (int ni=0;ni<4;ni++)
          acc[mi][ni] = __builtin_amdgcn_mfma_f32_16x16x32_bf16(af[mi], bf[ni], acc[mi][ni], 0,0,0);
      }
    }
    __syncthreads();
  }
  #pragma unroll
  for (int ni=0; ni<4; ++ni){
    int n = n0 + wc*64 + ni*16 + (lane&15);
    float bs = bsum[n];
    #pragma unroll
    for (int mi=0; mi<4; ++mi){
      int mb = m0 + wr*64 + mi*16 + (lane>>4)*4;
      #pragma unroll
      for (int r2=0;r2<4;r2++)
        pre[(size_t)(mb+r2)*DG_ + n] = __float2bfloat16(acc[mi][ni][r2] + bs);
    }
  }
}

// ---------------- encoder recurrence: 256 wgs = (dir, b), 512 thr ----------------
// thread t = (jj = t>>1, half = t&1). Each thread owns gate rows {jj, jj+256, jj+512, jj+768}
// over k-range [half*128, half*128+128). Weights: 4 rows x 128 fp8 = 128 VGPRs.
// __launch_bounds__(512,2): 2 waves/SIMD -> 256-VGPR cap, no spill.
__global__ __launch_bounds__(512, 2) void k_enc_rec(
    const __hip_bfloat16* __restrict__ pre, const uint32_t* __restrict__ whh8,
    float* __restrict__ SH, float* __restrict__ x0){
  int wg = blockIdx.x;
  int dir = wg >> 7, b = wg & 127;
  int t = threadIdx.x;
  int jj = t >> 1, half = t & 1;
  __shared__ float hbuf[2][256];

  uint32_t w[4][32];   // rows i,f,g,o ; 32 words = 128 fp8 each
  {
    const uint32_t* wbase = whh8 + ((size_t)dir*G_)*(E_/4);
    #pragma unroll
    for (int r=0;r<4;r++){
      const uint4* p = (const uint4*)(wbase + ((size_t)(jj + 256*r))*64 + half*32);
      #pragma unroll
      for (int i=0;i<8;i++){
        uint4 v = p[i];
        w[r][4*i]=v.x; w[r][4*i+1]=v.y; w[r][4*i+2]=v.z; w[r][4*i+3]=v.w;
      }
    }
  }
  hbuf[0][jj] = 0.f;  // both lanes of the pair write the same value
  float c = 0.f, sh = 0.f;
  const __hip_bfloat16* preB = pre + ((size_t)b*S_)*DG_ + dir*G_;
  int t0 = dir ? (S_-1) : 0;
  // half==0 lane carries pre for rows (i,f); half==1 lane carries (g,o)
  float p0 = __bfloat162float(preB[(size_t)t0*DG_ + jj + half*512]);
  float p1 = __bfloat162float(preB[(size_t)t0*DG_ + jj + half*512 + 256]);
  __syncthreads();

  int pb = 0;
  for (int s=0; s<S_; ++s){
    float a0=0.f, a1=0.f, a2=0.f, a3=0.f;   // partial dots: i,f,g,o
    const float4* h4 = (const float4*)hbuf[pb] + half*32;
    #pragma unroll
    for (int u=0; u<32; ++u){
      float4 hv = h4[u];
      float d0[4], d1[4], d2[4], d3[4];
      fp8x4_to_f32x4(w[0][u], d0);
      fp8x4_to_f32x4(w[1][u], d1);
      fp8x4_to_f32x4(w[2][u], d2);
      fp8x4_to_f32x4(w[3][u], d3);
      a0 = fmaf(d0[0],hv.x,a0); a0 = fmaf(d0[1],hv.y,a0);
      a0 = fmaf(d0[2],hv.z,a0); a0 = fmaf(d0[3],hv.w,a0);
      a1 = fmaf(d1[0],hv.x,a1); a1 = fmaf(d1[1],hv.y,a1);
      a1 = fmaf(d1[2],hv.z,a1); a1 = fmaf(d1[3],hv.w,a1);
      a2 = fmaf(d2[0],hv.x,a2); a2 = fmaf(d2[1],hv.y,a2);
      a2 = fmaf(d2[2],hv.z,a2); a2 = fmaf(d2[3],hv.w,a2);
      a3 = fmaf(d3[0],hv.x,a3); a3 = fmaf(d3[1],hv.y,a3);
      a3 = fmaf(d3[2],hv.z,a3); a3 = fmaf(d3[3],hv.w,a3);
    }
    // fold in pre-GEMM activations (each lane holds 2 of the 4 gate rows)
    a0 += half ? 0.f : p0;   // i
    a1 += half ? 0.f : p1;   // f
    a2 += half ? p0 : 0.f;   // g
    a3 += half ? p1 : 0.f;   // o
    // prefetch next step's pre
    if (s+1 < S_){
      int tn = dir ? (S_-2-s) : (s+1);
      p0 = __bfloat162float(preB[(size_t)tn*DG_ + jj + half*512]);
      p1 = __bfloat162float(preB[(size_t)tn*DG_ + jj + half*512 + 256]);
    }
    // combine k-halves across the lane pair
    a0 += __shfl_xor(a0, 1);
    a1 += __shfl_xor(a1, 1);
    a2 += __shfl_xor(a2, 1);
    a3 += __shfl_xor(a3, 1);
    float cn = sigm(a1)*c + sigm(a0)*tanh_f(a2);
    float hn = sigm(a3)*tanh_f(cn);
    c = cn;
    sh += hn;
    hbuf[pb^1][jj] = hn;   // both lanes write identical value
    if (half==0 && ((dir==0 && s==S_-1) || (dir==1 && s==0)))
      x0[(size_t)b*H2_ + dir*E_ + jj] = hn;
    __syncthreads();
    pb ^= 1;
  }
  if (half==0) SH[((size_t)dir*B_ + b)*E_ + jj] = sh;
}

// ---------------- decoder + ae_loss: 128 wgs = b, 512 thr = hidden dim ----------------
#define EPS_CONV 2e-6f
__global__ __launch_bounds__(512) void k_dec(
    const float* __restrict__ X, const uint4* __restrict__ wdt,
    const float* __restrict__ bsumd, const float* __restrict__ x0,
    const float* __restrict__ SX, const float* __restrict__ SX2,
    float* __restrict__ loss_b){
  int b = blockIdx.x, j = threadIdx.x;
  __shared__ _Float16 hl[512];
  __shared__ float red[512];
  __shared__ int s_any;
  float h = x0[(size_t)b*H2_ + j];
  hl[j] = (_Float16)h;
  float bi = bsumd[j], bg = bsumd[j+1024], bo = bsumd[j+1536];
  float sxp = 0.f, x2p = 0.f, lacc = 0.f;
  const float* xb = X + (size_t)b*S_*H2_;
  int done = S_;
  __syncthreads();
  for (int s=0; s<S_; ++s){
    if (j == 0) s_any = 0;
    float ai = bi, ag = bg, ao = bo;
    const uint4* hp = (const uint4*)hl;
    const uint4* wi = wdt + j;
    const uint4* wgp = wdt + j + 1024;
    const uint4* wo = wdt + j + 1536;
    #pragma unroll 8
    for (int u=0; u<64; ++u){
      uint4 hv = hp[u];
      uint4 a = wi[(size_t)u*DG_];
      uint4 g = wgp[(size_t)u*DG_];
      uint4 o = wo[(size_t)u*DG_];
      ai = dot2_f16(a.x, hv.x, ai); ai = dot2_f16(a.y, hv.y, ai);
      ai = dot2_f16(a.z, hv.z, ai); ai = dot2_f16(a.w, hv.w, ai);
      ag = dot2_f16(g.x, hv.x, ag); ag = dot2_f16(g.y, hv.y, ag);
      ag = dot2_f16(g.z, hv.z, ag); ag = dot2_f16(g.w, hv.w, ag);
      ao = dot2_f16(o.x, hv.x, ao); ao = dot2_f16(o.y, hv.y, ao);
      ao = dot2_f16(o.z, hv.z, ao); ao = dot2_f16(o.w, hv.w, ao);
    }
    float cc = sigm(ai) * tanh_f(ag);
    float hn = sigm(ao) * tanh_f(cc);
    float xv = xb[(size_t)s*H2_ + j];
    float dd = xv - hn;
    lacc += dd*dd; sxp += xv; x2p = fmaf(xv,xv,x2p);
    float delta = fabsf(hn - h);
    h = hn;
    __syncthreads();                      // dot reads of old hl done; s_any cleared
    hl[j] = (_Float16)h;
    if (__any(delta > EPS_CONV) && (j & 63) == 0) s_any = 1;
    __syncthreads();
    if (!s_any){ done = s+1; break; }
  }
  if (done < S_){
    size_t o = (size_t)b*H2_ + j;
    float rx = SX[o] - sxp, rx2 = SX2[o] - x2p;
    float rem = (float)(S_ - done);
    lacc += rx2 - 2.f*h*rx + rem*h*h;
  }
  red[j] = lacc;
  __syncthreads();
  for (int st=256; st>0; st>>=1){
    if (j < st) red[j] += red[j+st];
    __syncthreads();
  }
  if (j == 0) loss_b[b] = red[0];
}

// ---------------- output head ----------------
__global__ __launch_bounds__(256) void k_out(
    const float* __restrict__ SX, const float* __restrict__ SH,
    const float* __restrict__ outW, const float* __restrict__ outWb,
    const float* __restrict__ loss_b, float* __restrict__ out){
  int b = blockIdx.x, o = threadIdx.x;
  __shared__ float pooled[512];
  for (int d=o; d<512; d+=256){
    float v = SX[(size_t)b*H2_ + d];
    v += (d < E_) ? SH[(size_t)b*E_ + d] : SH[(size_t)(B_ + b)*E_ + (d - E_)];
    pooled[d] = v;
  }
  __syncthreads();
  const float4* w4 = (const float4*)(outW + (size_t)o*H2_);
  const float4* p4 = (const float4*)pooled;
  float acc = outWb[o];
  #pragma unroll 16
  for (int i=0;i<128;i++){
    float4 w = w4[i], p = p4[i];
    acc = fmaf(w.x,p.x,acc); acc = fmaf(w.y,p.y,acc);
    acc = fmaf(w.z,p.z,acc); acc = fmaf(w.w,p.w,acc);
  }
  out[(size_t)b*256 + o] = acc;
  if (b == 0 && o == 0){
    float L = 0.f;
    for (int i=0;i<B_;i++) L += loss_b[i];
    out[32768] = L / 33554432.f;
  }
}

extern "C" void kernel_launch(void* const* d_in, const int* in_sizes, int n_in,
                              void* d_out, int out_size, void* d_ws, size_t ws_size,
                              hipStream_t stream) {
  const float* X     = (const float*)d_in[0];
  const float* Wihf  = (const float*)d_in[1];
  const float* Whhf  = (const float*)d_in[2];
  const float* bihf  = (const float*)d_in[3];
  const float* bhhf  = (const float*)d_in[4];
  const float* Wihb  = (const float*)d_in[5];
  const float* Whhb  = (const float*)d_in[6];
  const float* bihb  = (const float*)d_in[7];
  const float* bhhb  = (const float*)d_in[8];
  const float* Wdec  = (const float*)d_in[9];
  const float* dbih  = (const float*)d_in[10];
  const float* dbhh  = (const float*)d_in[11];
  // d_in[12..15]: attW/attW_b/attU/attU_b are mathematically dead (softmax over size-1 axis)
  const float* outW  = (const float*)d_in[16];
  const float* outWb = (const float*)d_in[17];
  float* out = (float*)d_out;

  char* ws = (char*)d_ws;
  size_t off = 0;
  auto alloc = [&](size_t bytes){ void* p = ws + off; off += (bytes + 255) & ~(size_t)255; return p; };
  __hip_bfloat16* pre  = (__hip_bfloat16*)alloc((size_t)M_*DG_*2);   // 268 MB
  ushort* Wenc         = (ushort*)alloc((size_t)DG_*H2_*2);
  float* bsum          = (float*)alloc((size_t)DG_*4);
  uint8_t* whh8        = (uint8_t*)alloc((size_t)2*G_*E_);
  uint4* wdt           = (uint4*)alloc((size_t)64*DG_*16);
  float* bsumd         = (float*)alloc((size_t)DG_*4);
  float* SX            = (float*)alloc((size_t)B_*H2_*4);
  float* SX2           = (float*)alloc((size_t)B_*H2_*4);
  float* SH            = (float*)alloc((size_t)2*B_*E_*4);
  float* x0            = (float*)alloc((size_t)B_*H2_*4);
  float* loss_b        = (float*)alloc((size_t)B_*4);

  hipLaunchKernelGGL(k_prep_enc, dim3(DG_), dim3(512), 0, stream,
                     Wihf, Wihb, bihf, bhhf, bihb, bhhb, Wenc, bsum);
  hipLaunchKernelGGL(k_prep_whh, dim3(2*G_), dim3(E_), 0, stream, Whhf, Whhb, whh8);
  hipLaunchKernelGGL(k_prep_dec, dim3(DG_), dim3(64), 0, stream, Wdec, dbih, dbhh, wdt, bsumd);
  hipLaunchKernelGGL(k_xstat, dim3(B_), dim3(H2_), 0, stream, X, SX, SX2);
  hipLaunchKernelGGL(k_gemm_pre, dim3(16, 512), dim3(256), 0, stream, X, Wenc, bsum, pre);
  hipLaunchKernelGGL(k_enc_rec, dim3(256), dim3(512), 0, stream,
                     pre, (const uint32_t*)whh8, SH, x0);
  hipLaunchKernelGGL(k_dec, dim3(B_), dim3(512), 0, stream, X, wdt, bsumd, x0, SX, SX2, loss_b);
  hipLaunchKernelGGL(k_out, dim3(B_), dim3(256), 0, stream, SX, SH, outW, outWb, loss_b, out);
}

// Round 3
// 14395.714 us; speedup vs baseline: 2.8189x; 2.8189x over previous
//
#include <hip/hip_runtime.h>
#include <hip/hip_bf16.h>
#include <hip/hip_fp16.h>
#include <stdint.h>

#define B_ 128
#define S_ 512
#define E_ 256
#define H2_ 512
#define G_ 1024      // 4*E
#define DG_ 2048     // 4*H2
#define M_ (B_*S_)   // 65536

typedef float f32x4 __attribute__((ext_vector_type(4)));
typedef short s16x8 __attribute__((ext_vector_type(8)));
typedef _Float16 h16x2 __attribute__((ext_vector_type(2)));

__device__ __forceinline__ float sigm(float x){ return 1.f/(1.f+__expf(-x)); }
__device__ __forceinline__ float tanh_f(float x){ return 1.f - 2.f/(__expf(2.f*x)+1.f); }

// ---------------- fp8 e4m3fn encode/decode ----------------
__device__ __forceinline__ uint32_t enc_e4m3(float f){
  uint32_t u = __float_as_uint(f);
  uint32_t s = (u >> 24) & 0x80u;
  float af = fabsf(f);
  if (!(af > 0.f)) return s;
  if (af >= 448.f) return s | 0x7Eu;
  int ex = (int)((u >> 23) & 0xFF) - 127;
  uint32_t man = u & 0x7FFFFFu;
  int bexp = ex + 7;
  if (bexp <= 0){
    uint32_t qi = (uint32_t)rintf(af * 512.f);
    if (qi > 8u) qi = 8u;
    return s | qi;
  }
  uint32_t keep = man >> 20;
  uint32_t rest = man & 0xFFFFFu;
  const uint32_t half = 0x80000u;
  if (rest > half || (rest == half && (keep & 1u))) keep++;
  if (keep == 8u){ keep = 0u; bexp++; }
  if (bexp >= 16) return s | 0x7Eu;
  if (bexp == 15 && keep == 7u) keep = 6u; // avoid NaN encoding
  return s | ((uint32_t)bexp << 3) | keep;
}

__device__ __forceinline__ float dec_e4m3(uint32_t byte){
  uint32_t s = (byte & 0x80u) << 24;
  uint32_t e = (byte >> 3) & 0xFu;
  uint32_t m = byte & 7u;
  float v;
  if (e == 0) v = (float)m * 0.001953125f;
  else v = __uint_as_float(((e + 120u) << 23) | (m << 20));
  return __uint_as_float(__float_as_uint(v) | s);
}

__device__ __forceinline__ void fp8x4_to_f32x4(uint32_t w, float* o){
#if __has_builtin(__builtin_amdgcn_cvt_pk_f32_fp8)
  auto lo = __builtin_amdgcn_cvt_pk_f32_fp8((int)w, false);
  auto hi = __builtin_amdgcn_cvt_pk_f32_fp8((int)w, true);
  o[0]=lo[0]; o[1]=lo[1]; o[2]=hi[0]; o[3]=hi[1];
#else
  o[0]=dec_e4m3(w & 0xFFu); o[1]=dec_e4m3((w>>8)&0xFFu);
  o[2]=dec_e4m3((w>>16)&0xFFu); o[3]=dec_e4m3(w>>24);
#endif
}

__device__ __forceinline__ float dot2_f16(uint32_t a, uint32_t b, float acc){
#if __has_builtin(__builtin_amdgcn_fdot2)
  return __builtin_amdgcn_fdot2(__builtin_bit_cast(h16x2,a), __builtin_bit_cast(h16x2,b), acc, false);
#else
  __half2 ah = __builtin_bit_cast(__half2, a), bh = __builtin_bit_cast(__half2, b);
  float2 af = __half22float2(ah), bf = __half22float2(bh);
  return fmaf(af.x, bf.x, fmaf(af.y, bf.y, acc));
#endif
}

// ---------------- weight prep ----------------
__global__ __launch_bounds__(512) void k_prep_enc(
    const float* __restrict__ wf, const float* __restrict__ wb,
    const float* __restrict__ bihf, const float* __restrict__ bhhf,
    const float* __restrict__ bihb, const float* __restrict__ bhhb,
    ushort* __restrict__ Wenc, float* __restrict__ bsum){
  int n = blockIdx.x, d = threadIdx.x;
  const float* src = (n < G_) ? (wf + (size_t)n*H2_) : (wb + (size_t)(n-G_)*H2_);
  __hip_bfloat16 h = __float2bfloat16(src[d]);
  Wenc[(size_t)n*H2_ + d] = __builtin_bit_cast(ushort, h);
  if (d == 0) bsum[n] = (n < G_) ? (bihf[n] + bhhf[n]) : (bihb[n-G_] + bhhb[n-G_]);
}

__global__ __launch_bounds__(256) void k_prep_whh(
    const float* __restrict__ whf, const float* __restrict__ whb, uint8_t* __restrict__ whh8){
  int r = blockIdx.x; int d = threadIdx.x;
  int dir = r >> 10, g = r & 1023;
  float v = dir ? whb[(size_t)g*E_ + d] : whf[(size_t)g*E_ + d];
  whh8[((size_t)dir*G_ + g)*E_ + d] = (uint8_t)enc_e4m3(v);
}

__global__ __launch_bounds__(64) void k_prep_dec(
    const float* __restrict__ wd, const float* __restrict__ bih, const float* __restrict__ bhh,
    uint4* __restrict__ wdt, float* __restrict__ bsumd){
  int row = blockIdx.x, u = threadIdx.x; // u in [0,64)
  const float* src = wd + (size_t)row*H2_ + u*8;
  union { _Float16 h[8]; uint4 q; } pk;
  #pragma unroll
  for (int i=0;i<8;i++) pk.h[i] = (_Float16)src[i];
  wdt[(size_t)u*DG_ + row] = pk.q;
  if (u == 0) bsumd[row] = bih[row] + bhh[row];
}

// ---------------- input stats ----------------
__global__ __launch_bounds__(512) void k_xstat(
    const float* __restrict__ X, float* __restrict__ SX, float* __restrict__ SX2){
  int b = blockIdx.x, d = threadIdx.x;
  const float* xb = X + (size_t)b*S_*H2_;
  float s=0.f, s2=0.f;
  for (int t=0;t<S_;++t){ float v = xb[(size_t)t*H2_ + d]; s += v; s2 = fmaf(v,v,s2); }
  SX[(size_t)b*H2_+d]=s; SX2[(size_t)b*H2_+d]=s2;
}

// ---------------- pre-GEMM: pre[m][n] = X[m][:] . Wenc[n][:] + bsum[n] ----------------
__global__ __launch_bounds__(256) void k_gemm_pre(
    const float* __restrict__ X, const ushort* __restrict__ Wenc,
    const float* __restrict__ bsum, __hip_bfloat16* __restrict__ pre){
  __shared__ ushort As[128][64];
  __shared__ ushort Bs[128][64];
  int n0 = blockIdx.x * 128, m0 = blockIdx.y * 128;
  int tid = threadIdx.x, lane = tid & 63, wid = tid >> 6;
  int wr = wid >> 1, wc = wid & 1;
  f32x4 acc[4][4] = {};
  for (int kt=0; kt<8; ++kt){
    int k0 = kt*64;
    #pragma unroll
    for (int it=0; it<4; ++it){
      int slot = tid + it*256;
      int r = slot >> 3, c8 = (slot & 7)*8;
      const float* ap = X + (size_t)(m0+r)*512 + k0 + c8;
      float4 a0 = *(const float4*)ap;
      float4 a1 = *(const float4*)(ap+4);
      union { __hip_bfloat16 h[8]; uint4 q; } pk;
      pk.h[0]=__float2bfloat16(a0.x); pk.h[1]=__float2bfloat16(a0.y);
      pk.h[2]=__float2bfloat16(a0.z); pk.h[3]=__float2bfloat16(a0.w);
      pk.h[4]=__float2bfloat16(a1.x); pk.h[5]=__float2bfloat16(a1.y);
      pk.h[6]=__float2bfloat16(a1.z); pk.h[7]=__float2bfloat16(a1.w);
      *(uint4*)&As[r][c8] = pk.q;
      *(uint4*)&Bs[r][c8] = *(const uint4*)(Wenc + (size_t)(n0+r)*512 + k0 + c8);
    }
    __syncthreads();
    #pragma unroll
    for (int kk=0; kk<2; ++kk){
      int krow = kk*32 + (lane>>4)*8;
      s16x8 af[4], bf[4];
      #pragma unroll
      for (int mi=0;mi<4;mi++) af[mi] = *(const s16x8*)&As[wr*64+mi*16+(lane&15)][krow];
      #pragma unroll
      for (int ni=0;ni<4;ni++) bf[ni] = *(const s16x8*)&Bs[wc*64+ni*16+(lane&15)][krow];
      #pragma unroll
      for (int mi=0;mi<4;mi++){
        #pragma unroll
        for (int ni=0;ni<4;ni++)
          acc[mi][ni] = __builtin_amdgcn_mfma_f32_16x16x32_bf16(af[mi], bf[ni], acc[mi][ni], 0,0,0);
      }
    }
    __syncthreads();
  }
  #pragma unroll
  for (int ni=0; ni<4; ++ni){
    int n = n0 + wc*64 + ni*16 + (lane&15);
    float bs = bsum[n];
    #pragma unroll
    for (int mi=0; mi<4; ++mi){
      int mb = m0 + wr*64 + mi*16 + (lane>>4)*4;
      #pragma unroll
      for (int r2=0;r2<4;r2++)
        pre[(size_t)(mb+r2)*DG_ + n] = __float2bfloat16(acc[mi][ni][r2] + bs);
    }
  }
}

// ---------------- encoder recurrence v3 ----------------
// 256 wgs = (dir, b), 1024 threads = 16 waves. Thread t: jj = t>>2 (hidden unit),
// q = t&3. Rows: q<2 -> (jj [i], jj+256 [f]); q>=2 -> (jj+512 [g], jj+768 [o]).
// K-half: kh = q&1 -> k in [kh*128, kh*128+128). Weights: 2 rows x 128 fp8 = 64 VGPRs.
// Hard VGPR budget is 128 (4 waves/SIMD x 128 = full 512 pool) -> live set ~100 fits.
// Combine: shfl_xor(1) sums k-halves; shfl_xor(2) swaps (i,f)<->(g,o) across quad.
__global__ __launch_bounds__(1024, 4) void k_enc_rec(
    const __hip_bfloat16* __restrict__ pre, const uint8_t* __restrict__ whh8,
    float* __restrict__ SH, float* __restrict__ x0){
  int wg = blockIdx.x;
  int dir = wg >> 7, b = wg & 127;
  int t = threadIdx.x;
  int jj = t >> 2, q = t & 3, kh = q & 1;
  // h halves offset by 132 floats so the two per-wave broadcast addresses
  // hit different banks (128 floats apart = same banks).
  __shared__ float hbuf[2][264];

  uint32_t w0[32], w1[32];   // rowA, rowB ; 32 words = 128 fp8 each
  {
    int rA = (q & 2) ? (jj + 512) : jj;       // i or g
    const uint4* pa = (const uint4*)(whh8 + ((size_t)dir*G_ + rA)*E_ + kh*128);
    const uint4* pb = (const uint4*)(whh8 + ((size_t)dir*G_ + rA + 256)*E_ + kh*128);
    #pragma unroll
    for (int i=0;i<8;i++){
      uint4 va = pa[i]; w0[4*i]=va.x; w0[4*i+1]=va.y; w0[4*i+2]=va.z; w0[4*i+3]=va.w;
      uint4 vb = pb[i]; w1[4*i]=vb.x; w1[4*i+1]=vb.y; w1[4*i+2]=vb.z; w1[4*i+3]=vb.w;
    }
  }
  int slot = (jj < 128) ? jj : (jj + 4);
  if (q == 0) hbuf[0][slot] = 0.f;
  float c = 0.f, sh = 0.f;
  const __hip_bfloat16* preB = pre + ((size_t)b*S_)*DG_ + dir*G_;
  int rA_gate = (q & 2) ? (jj + 512) : jj;
  int t0 = dir ? (S_-1) : 0;
  float p0 = __bfloat162float(preB[(size_t)t0*DG_ + rA_gate]);
  float p1 = __bfloat162float(preB[(size_t)t0*DG_ + rA_gate + 256]);
  __syncthreads();

  int pb = 0;
  for (int s=0; s<S_; ++s){
    float a0 = 0.f, a1 = 0.f;   // partial dots for rowA, rowB
    const float4* h4 = (const float4*)(hbuf[pb] + kh*132);
    #pragma unroll
    for (int u=0; u<32; ++u){
      float4 hv = h4[u];
      float d0[4], d1[4];
      fp8x4_to_f32x4(w0[u], d0);
      fp8x4_to_f32x4(w1[u], d1);
      a0 = fmaf(d0[0],hv.x,a0); a0 = fmaf(d0[1],hv.y,a0);
      a0 = fmaf(d0[2],hv.z,a0); a0 = fmaf(d0[3],hv.w,a0);
      a1 = fmaf(d1[0],hv.x,a1); a1 = fmaf(d1[1],hv.y,a1);
      a1 = fmaf(d1[2],hv.z,a1); a1 = fmaf(d1[3],hv.w,a1);
    }
    // sum k-halves (lanes differing in bit0 share the same rows)
    a0 += __shfl_xor(a0, 1);
    a1 += __shfl_xor(a1, 1);
    // fold in pre-GEMM activations for this thread's rows
    a0 += p0;
    a1 += p1;
    // prefetch next step's pre
    if (s+1 < S_){
      int tn = dir ? (S_-2-s) : (s+1);
      p0 = __bfloat162float(preB[(size_t)tn*DG_ + rA_gate]);
      p1 = __bfloat162float(preB[(size_t)tn*DG_ + rA_gate + 256]);
    }
    // swap gate pairs across quad: (i,f) <-> (g,o)
    float b0 = __shfl_xor(a0, 2);
    float b1 = __shfl_xor(a1, 2);
    float ai = (q & 2) ? b0 : a0;
    float af = (q & 2) ? b1 : a1;
    float ag = (q & 2) ? a0 : b0;
    float ao = (q & 2) ? a1 : b1;
    float cn = sigm(af)*c + sigm(ai)*tanh_f(ag);
    float hn = sigm(ao)*tanh_f(cn);
    c = cn;
    sh += hn;
    if (q == 0){
      hbuf[pb^1][slot] = hn;
      if ((dir==0 && s==S_-1) || (dir==1 && s==0))
        x0[(size_t)b*H2_ + dir*E_ + jj] = hn;
    }
    __syncthreads();
    pb ^= 1;
  }
  if (q == 0) SH[((size_t)dir*B_ + b)*E_ + jj] = sh;
}

// ---------------- decoder + ae_loss: 128 wgs = b, 512 thr = hidden dim ----------------
#define EPS_CONV 2e-6f
__global__ __launch_bounds__(512) void k_dec(
    const float* __restrict__ X, const uint4* __restrict__ wdt,
    const float* __restrict__ bsumd, const float* __restrict__ x0,
    const float* __restrict__ SX, const float* __restrict__ SX2,
    float* __restrict__ loss_b){
  int b = blockIdx.x, j = threadIdx.x;
  __shared__ _Float16 hl[512];
  __shared__ float red[512];
  __shared__ int s_any;
  float h = x0[(size_t)b*H2_ + j];
  hl[j] = (_Float16)h;
  float bi = bsumd[j], bg = bsumd[j+1024], bo = bsumd[j+1536];
  float sxp = 0.f, x2p = 0.f, lacc = 0.f;
  const float* xb = X + (size_t)b*S_*H2_;
  int done = S_;
  __syncthreads();
  for (int s=0; s<S_; ++s){
    if (j == 0) s_any = 0;
    float ai = bi, ag = bg, ao = bo;
    const uint4* hp = (const uint4*)hl;
    const uint4* wi = wdt + j;
    const uint4* wgp = wdt + j + 1024;
    const uint4* wo = wdt + j + 1536;
    #pragma unroll 8
    for (int u=0; u<64; ++u){
      uint4 hv = hp[u];
      uint4 a = wi[(size_t)u*DG_];
      uint4 g = wgp[(size_t)u*DG_];
      uint4 o = wo[(size_t)u*DG_];
      ai = dot2_f16(a.x, hv.x, ai); ai = dot2_f16(a.y, hv.y, ai);
      ai = dot2_f16(a.z, hv.z, ai); ai = dot2_f16(a.w, hv.w, ai);
      ag = dot2_f16(g.x, hv.x, ag); ag = dot2_f16(g.y, hv.y, ag);
      ag = dot2_f16(g.z, hv.z, ag); ag = dot2_f16(g.w, hv.w, ag);
      ao = dot2_f16(o.x, hv.x, ao); ao = dot2_f16(o.y, hv.y, ao);
      ao = dot2_f16(o.z, hv.z, ao); ao = dot2_f16(o.w, hv.w, ao);
    }
    float cc = sigm(ai) * tanh_f(ag);
    float hn = sigm(ao) * tanh_f(cc);
    float xv = xb[(size_t)s*H2_ + j];
    float dd = xv - hn;
    lacc += dd*dd; sxp += xv; x2p = fmaf(xv,xv,x2p);
    float delta = fabsf(hn - h);
    h = hn;
    __syncthreads();                      // dot reads of old hl done; s_any cleared
    hl[j] = (_Float16)h;
    if (__any(delta > EPS_CONV) && (j & 63) == 0) s_any = 1;
    __syncthreads();
    if (!s_any){ done = s+1; break; }
  }
  if (done < S_){
    size_t o = (size_t)b*H2_ + j;
    float rx = SX[o] - sxp, rx2 = SX2[o] - x2p;
    float rem = (float)(S_ - done);
    lacc += rx2 - 2.f*h*rx + rem*h*h;
  }
  red[j] = lacc;
  __syncthreads();
  for (int st=256; st>0; st>>=1){
    if (j < st) red[j] += red[j+st];
    __syncthreads();
  }
  if (j == 0) loss_b[b] = red[0];
}

// ---------------- output head ----------------
__global__ __launch_bounds__(256) void k_out(
    const float* __restrict__ SX, const float* __restrict__ SH,
    const float* __restrict__ outW, const float* __restrict__ outWb,
    const float* __restrict__ loss_b, float* __restrict__ out){
  int b = blockIdx.x, o = threadIdx.x;
  __shared__ float pooled[512];
  for (int d=o; d<512; d+=256){
    float v = SX[(size_t)b*H2_ + d];
    v += (d < E_) ? SH[(size_t)b*E_ + d] : SH[(size_t)(B_ + b)*E_ + (d - E_)];
    pooled[d] = v;
  }
  __syncthreads();
  const float4* w4 = (const float4*)(outW + (size_t)o*H2_);
  const float4* p4 = (const float4*)pooled;
  float acc = outWb[o];
  #pragma unroll 16
  for (int i=0;i<128;i++){
    float4 w = w4[i], p = p4[i];
    acc = fmaf(w.x,p.x,acc); acc = fmaf(w.y,p.y,acc);
    acc = fmaf(w.z,p.z,acc); acc = fmaf(w.w,p.w,acc);
  }
  out[(size_t)b*256 + o] = acc;
  if (b == 0 && o == 0){
    float L = 0.f;
    for (int i=0;i<B_;i++) L += loss_b[i];
    out[32768] = L / 33554432.f;
  }
}

extern "C" void kernel_launch(void* const* d_in, const int* in_sizes, int n_in,
                              void* d_out, int out_size, void* d_ws, size_t ws_size,
                              hipStream_t stream) {
  const float* X     = (const float*)d_in[0];
  const float* Wihf  = (const float*)d_in[1];
  const float* Whhf  = (const float*)d_in[2];
  const float* bihf  = (const float*)d_in[3];
  const float* bhhf  = (const float*)d_in[4];
  const float* Wihb  = (const float*)d_in[5];
  const float* Whhb  = (const float*)d_in[6];
  const float* bihb  = (const float*)d_in[7];
  const float* bhhb  = (const float*)d_in[8];
  const float* Wdec  = (const float*)d_in[9];
  const float* dbih  = (const float*)d_in[10];
  const float* dbhh  = (const float*)d_in[11];
  // d_in[12..15]: attW/attW_b/attU/attU_b are mathematically dead (softmax over size-1 axis)
  const float* outW  = (const float*)d_in[16];
  const float* outWb = (const float*)d_in[17];
  float* out = (float*)d_out;

  char* ws = (char*)d_ws;
  size_t off = 0;
  auto alloc = [&](size_t bytes){ void* p = ws + off; off += (bytes + 255) & ~(size_t)255; return p; };
  __hip_bfloat16* pre  = (__hip_bfloat16*)alloc((size_t)M_*DG_*2);   // 268 MB
  ushort* Wenc         = (ushort*)alloc((size_t)DG_*H2_*2);
  float* bsum          = (float*)alloc((size_t)DG_*4);
  uint8_t* whh8        = (uint8_t*)alloc((size_t)2*G_*E_);
  uint4* wdt           = (uint4*)alloc((size_t)64*DG_*16);
  float* bsumd         = (float*)alloc((size_t)DG_*4);
  float* SX            = (float*)alloc((size_t)B_*H2_*4);
  float* SX2           = (float*)alloc((size_t)B_*H2_*4);
  float* SH            = (float*)alloc((size_t)2*B_*E_*4);
  float* x0            = (float*)alloc((size_t)B_*H2_*4);
  float* loss_b        = (float*)alloc((size_t)B_*4);

  hipLaunchKernelGGL(k_prep_enc, dim3(DG_), dim3(512), 0, stream,
                     Wihf, Wihb, bihf, bhhf, bihb, bhhb, Wenc, bsum);
  hipLaunchKernelGGL(k_prep_whh, dim3(2*G_), dim3(E_), 0, stream, Whhf, Whhb, whh8);
  hipLaunchKernelGGL(k_prep_dec, dim3(DG_), dim3(64), 0, stream, Wdec, dbih, dbhh, wdt, bsumd);
  hipLaunchKernelGGL(k_xstat, dim3(B_), dim3(H2_), 0, stream, X, SX, SX2);
  hipLaunchKernelGGL(k_gemm_pre, dim3(16, 512), dim3(256), 0, stream, X, Wenc, bsum, pre);
  hipLaunchKernelGGL(k_enc_rec, dim3(256), dim3(1024), 0, stream,
                     pre, whh8, SH, x0);
  hipLaunchKernelGGL(k_dec, dim3(B_), dim3(512), 0, stream, X, wdt, bsumd, x0, SX, SX2, loss_b);
  hipLaunchKernelGGL(k_out, dim3(B_), dim3(256), 0, stream, SX, SH, outW, outWb, loss_b, out);
}